// Round 21
// baseline (216.456 us; speedup 1.0000x reference)
//
#include <hip/hip_runtime.h>

typedef unsigned short u16;
typedef unsigned int u32;
typedef __attribute__((ext_vector_type(8))) short bf16x8;
typedef __attribute__((ext_vector_type(4))) float f32x4;

__device__ __forceinline__ u16 f2bf(float f) {
  u32 u = __float_as_uint(f);
  u += 0x7fffu + ((u >> 16) & 1u);
  return (u16)(u >> 16);
}
__device__ __forceinline__ float bf2f(short h) {
  return __uint_as_float(((u32)(u16)h) << 16);
}

// ---------------- convert x: f32 -> bf16 ----------------
__global__ __launch_bounds__(256) void k_cvt(const float* __restrict__ in, u16* __restrict__ out, int n) {
  int idx = (blockIdx.x * 256 + threadIdx.x) * 8;
  if (idx >= n) return;
  float4 a = *(const float4*)&in[idx];
  float4 b = *(const float4*)&in[idx + 4];
  union { u16 h[8]; uint4 v; } t;
  t.h[0] = f2bf(a.x); t.h[1] = f2bf(a.y); t.h[2] = f2bf(a.z); t.h[3] = f2bf(a.w);
  t.h[4] = f2bf(b.x); t.h[5] = f2bf(b.y); t.h[6] = f2bf(b.z); t.h[7] = f2bf(b.w);
  *(uint4*)&out[idx] = t.v;
}

// ---------------- transpose+convert: out[c][r] = bf16(in[r][c]) ----------------
__global__ __launch_bounds__(256) void k_tcvt(const float* __restrict__ in, u16* __restrict__ out, int R, int C) {
  __shared__ u16 T[64 * 72];
  int t = threadIdx.x;
  int r0 = blockIdx.y * 64, c0 = blockIdx.x * 64;
  for (int i = 0; i < 4; i++) {
    int cc = i * 256 + t; int r = cc >> 4; int s = cc & 15;
    float4 v = *(const float4*)&in[(size_t)(r0 + r) * C + c0 + s * 4];
    T[r * 72 + s * 4 + 0] = f2bf(v.x);
    T[r * 72 + s * 4 + 1] = f2bf(v.y);
    T[r * 72 + s * 4 + 2] = f2bf(v.z);
    T[r * 72 + s * 4 + 3] = f2bf(v.w);
  }
  __syncthreads();
  for (int i = 0; i < 2; i++) {
    int cc = i * 256 + t; int c = cc >> 3; int s2 = cc & 7;
    union { u16 h[8]; uint4 v; } tmp;
    for (int e = 0; e < 8; e++) tmp.h[e] = T[(s2 * 8 + e) * 72 + c];
    *(uint4*)&out[(size_t)(c0 + c) * R + r0 + s2 * 8] = tmp.v;
  }
}

// ---------------- transpose v-part of qkv into Vt[512][8192] ----------------
__global__ __launch_bounds__(256) void k_tv(const u16* __restrict__ qkv, u16* __restrict__ vt) {
  __shared__ u16 T[64 * 72];
  int t = threadIdx.x;
  int r0 = blockIdx.y * 64, d0 = blockIdx.x * 64;
  for (int i = 0; i < 2; i++) {
    int cc = i * 256 + t; int r = cc >> 3; int s = cc & 7;
    *(uint4*)&T[r * 72 + s * 8] = *(const uint4*)&qkv[(size_t)(r0 + r) * 1536 + 1024 + d0 + s * 8];
  }
  __syncthreads();
  for (int i = 0; i < 2; i++) {
    int cc = i * 256 + t; int d = cc >> 3; int s2 = cc & 7;
    union { u16 h[8]; uint4 v; } tmp;
    for (int e = 0; e < 8; e++) tmp.h[e] = T[(s2 * 8 + e) * 72 + d];
    *(uint4*)&vt[(size_t)(d0 + d) * 8192 + r0 + s2 * 8] = tmp.v;
  }
}

// ---------------- GEMM (m97): C = A[M,K] @ Bt[N,K]^T + bias ----------------
__global__ __launch_bounds__(256) void k_gemm(const u16* __restrict__ A, const u16* __restrict__ Bt,
                                              const float* __restrict__ bias,
                                              u16* __restrict__ Cb, float* __restrict__ Cf,
                                              int M, int N, int K) {
  __shared__ u16 As[128 * 64];
  __shared__ u16 Bs[128 * 64];
  const int t = threadIdx.x;
  const int l = t & 63, w = t >> 6;
  const int l16 = l & 15, g = l >> 4;
  const int m0 = blockIdx.y * 128, n0 = blockIdx.x * 128;
  const int wr = (w >> 1) * 64, wc = (w & 1) * 64;
  f32x4 acc[4][4] = {};
  for (int kk = 0; kk < K; kk += 64) {
    __syncthreads();
#pragma unroll
    for (int i = 0; i < 4; i++) {
      int c = i * 256 + t;
      int r = c >> 3, g2 = c & 7;
      int sg = g2 ^ (r & 7);
      __builtin_amdgcn_global_load_lds(
          (const __attribute__((address_space(1))) u32*)(A + (size_t)(m0 + r) * K + kk + sg * 8),
          (__attribute__((address_space(3))) u32*)&As[c * 8], 16, 0, 0);
      __builtin_amdgcn_global_load_lds(
          (const __attribute__((address_space(1))) u32*)(Bt + (size_t)(n0 + r) * K + kk + sg * 8),
          (__attribute__((address_space(3))) u32*)&Bs[c * 8], 16, 0, 0);
    }
    __syncthreads();
#pragma unroll
    for (int kh = 0; kh < 2; kh++) {
      bf16x8 a[4];
#pragma unroll
      for (int mi = 0; mi < 4; mi++) {
        int row = wr + 16 * mi + l16;
        int s = (kh * 4 + g) ^ (row & 7);
        a[mi] = *(const bf16x8*)&As[row * 64 + s * 8];
      }
#pragma unroll
      for (int ni = 0; ni < 4; ni++) {
        int row = wc + 16 * ni + l16;
        int s = (kh * 4 + g) ^ (row & 7);
        bf16x8 b = *(const bf16x8*)&Bs[row * 64 + s * 8];
#pragma unroll
        for (int mi = 0; mi < 4; mi++)
          acc[mi][ni] = __builtin_amdgcn_mfma_f32_16x16x32_bf16(a[mi], b, acc[mi][ni], 0, 0, 0);
      }
    }
  }
#pragma unroll
  for (int ni = 0; ni < 4; ni++) {
    int col = n0 + wc + 16 * ni + l16;
    float bv = bias[col];
#pragma unroll
    for (int mi = 0; mi < 4; mi++) {
      int row0 = m0 + wr + 16 * mi + 4 * g;
#pragma unroll
      for (int r = 0; r < 4; r++) {
        float v = acc[mi][ni][r] + bv;
        if (Cf) Cf[(size_t)(row0 + r) * N + col] = v;
        else    Cb[(size_t)(row0 + r) * N + col] = f2bf(v);
      }
    }
  }
}

// ---------------- k_qkp: P = exp2(C*Q@K^T masked); XCD-chunked flat triangle grid ----------------
// hardware id h -> L = (h%8)*260 + h/8 (bijective, 2080 = 8*260): 260 consecutive slots per XCD.
// slot s = 2079 - L (long rows first); bi = floor((sqrt(8s+1)-1)/2), bj = s - bi(bi+1)/2.
__global__ __launch_bounds__(256, 4) void k_qkp(const u16* __restrict__ qkv,
                                                u16* __restrict__ sA, u16* __restrict__ sB, u16* __restrict__ sC,
                                                int nB, float* __restrict__ psum) {
  __shared__ u16 As[128 * 64];
  __shared__ u16 Bs[128 * 64];
  __shared__ float psL[2][128];
  const int h = (int)blockIdx.x;
  const int L = (h & 7) * 260 + (h >> 3);     // XCD-chunked remap
  const int s0 = 2079 - L;
  int bi = (int)((__builtin_sqrtf(8.0f * s0 + 1.0f) - 1.0f) * 0.5f);
  while ((bi + 1) * (bi + 2) / 2 <= s0) ++bi;
  while (bi * (bi + 1) / 2 > s0) --bi;
  const int bj = s0 - bi * (bi + 1) / 2;
  const int slot = s0;
  const int t = threadIdx.x;
  const int l = t & 63, w = t >> 6;
  const int l16 = l & 15, g = l >> 4;
  const int m0 = bi * 128, n0 = bj * 128;
  const int wr = (w >> 1) * 64, wc = (w & 1) * 64;
  f32x4 acc[4][4] = {};
  for (int kk = 0; kk < 512; kk += 64) {
    __syncthreads();
#pragma unroll
    for (int i = 0; i < 4; i++) {
      int c = i * 256 + t;
      int r = c >> 3, g2 = c & 7;
      int sg = g2 ^ (r & 7);
      __builtin_amdgcn_global_load_lds(
          (const __attribute__((address_space(1))) u32*)(qkv + (size_t)(m0 + r) * 1536 + kk + sg * 8),
          (__attribute__((address_space(3))) u32*)&As[c * 8], 16, 0, 0);
      __builtin_amdgcn_global_load_lds(
          (const __attribute__((address_space(1))) u32*)(qkv + (size_t)(n0 + r) * 1536 + 512 + kk + sg * 8),
          (__attribute__((address_space(3))) u32*)&Bs[c * 8], 16, 0, 0);
    }
    __syncthreads();
#pragma unroll
    for (int kh = 0; kh < 2; kh++) {
      bf16x8 a[4];
#pragma unroll
      for (int mi = 0; mi < 4; mi++) {
        int row = wr + 16 * mi + l16;
        int s = (kh * 4 + g) ^ (row & 7);
        a[mi] = *(const bf16x8*)&As[row * 64 + s * 8];
      }
#pragma unroll
      for (int ni = 0; ni < 4; ni++) {
        int row = wc + 16 * ni + l16;
        int s = (kh * 4 + g) ^ (row & 7);
        bf16x8 b = *(const bf16x8*)&Bs[row * 64 + s * 8];
#pragma unroll
        for (int mi = 0; mi < 4; mi++)
          acc[mi][ni] = __builtin_amdgcn_mfma_f32_16x16x32_bf16(a[mi], b, acc[mi][ni], 0, 0, 0);
      }
    }
  }
  const float C2 = 0.063758718f;              // (1/sqrt(512)) * log2(e)
#pragma unroll
  for (int mi = 0; mi < 4; mi++)
#pragma unroll
    for (int r = 0; r < 4; r++) {
      float s = 0.f;
#pragma unroll
      for (int ni = 0; ni < 4; ni++) {
        float v = acc[mi][ni][r] * C2;
        if (bi == bj && (wc + 16 * ni + l16) > (wr + 16 * mi + 4 * g + r)) v = -1.0e10f;
        float p = __builtin_exp2f(v);
        acc[mi][ni][r] = p;
        s += p;
      }
#pragma unroll
      for (int off = 1; off < 16; off <<= 1) s += __shfl_xor(s, off);
      if (l16 == 0) psL[w & 1][wr + 16 * mi + 4 * g + r] = s;
    }
  __syncthreads();
  if (t < 128) psum[slot * 128 + t] = psL[0][t] + psL[1][t];
  u16* sp = slot < 608 ? sA + (size_t)slot * 16384
          : (slot - 608) < nB ? sB + (size_t)(slot - 608) * 16384
          : sC + (size_t)(slot - 608 - nB) * 16384;
#pragma unroll
  for (int ni = 0; ni < 4; ni++)
#pragma unroll
    for (int mi = 0; mi < 4; mi++)
#pragma unroll
      for (int r = 0; r < 4; r++)
        sp[(wr + 16 * mi + 4 * g + r) * 128 + wc + 16 * ni + l16] = f2bf(acc[mi][ni][r]);
}

// ---------------- k_inv: invl[row] = 1 / sum_bj psum ----------------
__global__ __launch_bounds__(128) void k_inv(const float* __restrict__ psum, float* __restrict__ invl) {
  const int bi = blockIdx.x, t = threadIdx.x;
  const int base = (bi * (bi + 1)) / 2;
  float s = 0.f;
  for (int bj = 0; bj <= bi; bj++) s += psum[(base + bj) * 128 + t];
  invl[bi * 128 + t] = 1.0f / s;
}

// ---------------- k_pv4: 4-segment balanced split over long||short walk ----------------
__global__ __launch_bounds__(256, 4) void k_pv4(const u16* __restrict__ sA, const u16* __restrict__ sB,
                                                const u16* __restrict__ sC, int nB,
                                                const u16* __restrict__ vt, u16* __restrict__ part) {
  __shared__ u16 As[128 * 64];
  __shared__ u16 Bs[128 * 64];
  const int gx = blockIdx.x;
  const int p = gx >> 4, nj = (gx >> 2) & 3, seg = gx & 3;
  const int L = 2 * (64 - p);
  const int SEG[5] = {0, 33, 65, 98, 130};
  const int S0 = SEG[seg], E0 = SEG[seg + 1];
  const int n0 = nj * 128;
  const int t = threadIdx.x;
  const int l = t & 63, w = t >> 6;
  const int l16 = l & 15, g = l >> 4;
  const int wr = (w >> 1) * 64, wc = (w & 1) * 64;
  const int pb = (p * 4 + nj) * 5;
  f32x4 acc[4][4];

  auto zero = [&]() {
#pragma unroll
    for (int mi = 0; mi < 4; mi++)
#pragma unroll
      for (int ni = 0; ni < 4; ni++) acc[mi][ni] = (f32x4){0.f, 0.f, 0.f, 0.f};
  };
  auto runseg = [&](int bi, int ks0, int ks1) {
    const int slotBase = (bi * (bi + 1)) / 2;
    for (int ks = ks0; ks < ks1; ++ks) {
      const int s_ = slotBase + (ks >> 1);
      const u16* sp = s_ < 608 ? sA + (size_t)s_ * 16384
                    : (s_ - 608) < nB ? sB + (size_t)(s_ - 608) * 16384
                    : sC + (size_t)(s_ - 608 - nB) * 16384;
      const int ko = (ks & 1) * 64;
      const int kk = ks * 64;
      __syncthreads();
#pragma unroll
      for (int i = 0; i < 4; i++) {
        int c = i * 256 + t;
        int r = c >> 3, g2 = c & 7;
        int sg = g2 ^ (r & 7);
        __builtin_amdgcn_global_load_lds(
            (const __attribute__((address_space(1))) u32*)(sp + r * 128 + ko + sg * 8),
            (__attribute__((address_space(3))) u32*)&As[c * 8], 16, 0, 0);
        __builtin_amdgcn_global_load_lds(
            (const __attribute__((address_space(1))) u32*)(vt + (size_t)(n0 + r) * 8192 + kk + sg * 8),
            (__attribute__((address_space(3))) u32*)&Bs[c * 8], 16, 0, 0);
      }
      __syncthreads();
#pragma unroll
      for (int kh = 0; kh < 2; kh++) {
        bf16x8 a[4];
#pragma unroll
        for (int mi = 0; mi < 4; mi++) {
          int row = wr + 16 * mi + l16;
          int s2 = (kh * 4 + g) ^ (row & 7);
          a[mi] = *(const bf16x8*)&As[row * 64 + s2 * 8];
        }
#pragma unroll
        for (int ni = 0; ni < 4; ni++) {
          int row = wc + 16 * ni + l16;
          int s2 = (kh * 4 + g) ^ (row & 7);
          bf16x8 b = *(const bf16x8*)&Bs[row * 64 + s2 * 8];
#pragma unroll
          for (int mi = 0; mi < 4; mi++)
            acc[mi][ni] = __builtin_amdgcn_mfma_f32_16x16x32_bf16(a[mi], b, acc[mi][ni], 0, 0, 0);
        }
      }
    }
  };
  auto write_partial = [&](int q) {
    u16* dst = part + (size_t)(pb + q) * 16384;
#pragma unroll
    for (int mi = 0; mi < 4; mi++)
#pragma unroll
      for (int ni = 0; ni < 4; ni++)
#pragma unroll
        for (int r = 0; r < 4; r++)
          dst[(wr + 16 * mi + 4 * g + r) * 128 + wc + 16 * ni + l16] = f2bf(acc[mi][ni][r]);
  };

  const int biL = 63 - p, biS = p;
  const int lE = min(E0, L);
  const int sS = max(S0, L);
  if (S0 < L) {
    zero();
    runseg(biL, S0, lE);
    write_partial(seg);
    if (sS < E0) {
      zero();
      runseg(biS, sS - L, E0 - L);
      write_partial(4);
    }
  } else {
    zero();
    runseg(biS, S0 - L, E0 - L);
    write_partial(seg);
  }
}

// ---------------- k_compv: sum partials, normalize, write Ob ----------------
__global__ __launch_bounds__(256) void k_compv(const u16* __restrict__ part,
                                               const float* __restrict__ invl, u16* __restrict__ Ob) {
  const int b = blockIdx.x;
  const int which = b >> 7, idx = b & 127;
  const int p = idx >> 2, nj = idx & 3;
  const int bi = which ? p : 63 - p;
  const int m0 = bi * 128, n0 = nj * 128;
  const int L = 2 * (64 - p);
  const int SEG[5] = {0, 33, 65, 98, 130};
  const int pb = (p * 4 + nj) * 5;
  int inc[5];
  int spans = 0;
  for (int s = 0; s < 4; s++) {
    if (which == 0) inc[s] = (SEG[s] < L);
    else            inc[s] = (SEG[s] >= L);
    if (SEG[s] < L && SEG[s + 1] > L) spans = 1;
  }
  inc[4] = which ? spans : 0;
  const int t = threadIdx.x;
#pragma unroll
  for (int e = 0; e < 8; e++) {
    int pos = (e * 256 + t) * 8;
    int row = pos >> 7, col = pos & 127;
    float o[8] = {};
    for (int q = 0; q < 5; q++) {
      if (!inc[q]) continue;
      const uint4* src = (const uint4*)(part + (size_t)(pb + q) * 16384);
      uint4 v = src[pos >> 3];
      union { uint4 u; u16 h[8]; } un; un.u = v;
#pragma unroll
      for (int j = 0; j < 8; j++) o[j] += bf2f(un.h[j]);
    }
    float inv = invl[m0 + row];
    union { u16 h[8]; uint4 u; } pk;
#pragma unroll
    for (int j = 0; j < 8; j++) pk.h[j] = f2bf(o[j] * inv);
    *(uint4*)&Ob[(size_t)(m0 + row) * 512 + n0 + col] = pk.u;
  }
}

extern "C" void kernel_launch(void* const* d_in, const int* in_sizes, int n_in,
                              void* d_out, int out_size, void* d_ws, size_t ws_size,
                              hipStream_t stream) {
  const float* x     = (const float*)d_in[0];
  const float* w_qkv = (const float*)d_in[1];
  const float* b_qkv = (const float*)d_in[2];
  const float* w_out = (const float*)d_in[3];
  const float* b_out = (const float*)d_in[4];
  float* out = (float*)d_out;
  char* ws = (char*)d_ws;
  // base layout
  u16* xb    = (u16*)(ws);               // [8192][1024] bf16 (dead after gemm1 -> P region A)
  u16* wqkvT = (u16*)(ws + 16777216);    // [1536][1024] bf16 (dead after gemm1 -> P region A)
  u16* woutT = (u16*)(ws + 19922944);    // [1024][512]  bf16 (live to the end)
  u16* qkv   = (u16*)(ws + 20971520);    // [8192][1536] bf16 (dead after k_qkp -> pv4 partials)
  u16* vt    = (u16*)(ws + 46137344);    // [512][8192]  bf16
  u16* Ob    = (u16*)(ws + 54525952);    // [8192][512]  bf16

  // P slots: 2080 x 32KB. A: 608 slots; B: tail of ws; C: d_out. psum/invl in d_out after C.
  u16* sA = (u16*)ws;
  u16* sB = (u16*)(ws + 62914560);
  long nBl = ((long)ws_size - 62914560) / 32768;
  int nB = nBl > 1472 ? 1472 : (int)(nBl < 0 ? 0 : nBl);
  int nC = 2080 - 608 - nB; if (nC < 0) nC = 0;
  u16* sC = (u16*)d_out;
  float* psum = (float*)((u16*)d_out + (size_t)nC * 16384);
  float* invl = psum + 2080 * 128;
  // pv4 partials: 640 x 32KB bf16 = 20.97 MB in dead qkv region (25.17 MB)
  u16* part = (u16*)(ws + 20971520);

  k_cvt<<<4096, 256, 0, stream>>>(x, xb, 8192 * 1024);
  k_tcvt<<<dim3(24, 16), 256, 0, stream>>>(w_qkv, wqkvT, 1024, 1536);
  k_tcvt<<<dim3(16, 8), 256, 0, stream>>>(w_out, woutT, 512, 1024);
  k_gemm<<<dim3(12, 64), 256, 0, stream>>>(xb, wqkvT, b_qkv, qkv, nullptr, 8192, 1536, 1024);
  k_tv<<<dim3(8, 128), 256, 0, stream>>>(qkv, vt);
  k_qkp<<<2080, 256, 0, stream>>>(qkv, sA, sB, sC, nB, psum);
  k_inv<<<64, 128, 0, stream>>>(psum, invl);
  k_pv4<<<512, 256, 0, stream>>>(sA, sB, sC, nB, vt, part);
  k_compv<<<256, 256, 0, stream>>>(part, invl, Ob);
  k_gemm<<<dim3(8, 64), 256, 0, stream>>>(Ob, woutT, b_out, nullptr, out, 8192, 1024, 512);
}

// Round 22
// 202.731 us; speedup vs baseline: 1.0677x; 1.0677x over previous
//
#include <hip/hip_runtime.h>

typedef unsigned short u16;
typedef unsigned int u32;
typedef __attribute__((ext_vector_type(8))) short bf16x8;
typedef __attribute__((ext_vector_type(4))) float f32x4;

__device__ __forceinline__ u16 f2bf(float f) {
  u32 u = __float_as_uint(f);
  u += 0x7fffu + ((u >> 16) & 1u);
  return (u16)(u >> 16);
}
__device__ __forceinline__ float bf2f(short h) {
  return __uint_as_float(((u32)(u16)h) << 16);
}

// ---------------- convert x: f32 -> bf16 ----------------
__global__ __launch_bounds__(256) void k_cvt(const float* __restrict__ in, u16* __restrict__ out, int n) {
  int idx = (blockIdx.x * 256 + threadIdx.x) * 8;
  if (idx >= n) return;
  float4 a = *(const float4*)&in[idx];
  float4 b = *(const float4*)&in[idx + 4];
  union { u16 h[8]; uint4 v; } t;
  t.h[0] = f2bf(a.x); t.h[1] = f2bf(a.y); t.h[2] = f2bf(a.z); t.h[3] = f2bf(a.w);
  t.h[4] = f2bf(b.x); t.h[5] = f2bf(b.y); t.h[6] = f2bf(b.z); t.h[7] = f2bf(b.w);
  *(uint4*)&out[idx] = t.v;
}

// ---------------- transpose+convert: out[c][r] = bf16(in[r][c]) ----------------
__global__ __launch_bounds__(256) void k_tcvt(const float* __restrict__ in, u16* __restrict__ out, int R, int C) {
  __shared__ u16 T[64 * 72];
  int t = threadIdx.x;
  int r0 = blockIdx.y * 64, c0 = blockIdx.x * 64;
  for (int i = 0; i < 4; i++) {
    int cc = i * 256 + t; int r = cc >> 4; int s = cc & 15;
    float4 v = *(const float4*)&in[(size_t)(r0 + r) * C + c0 + s * 4];
    T[r * 72 + s * 4 + 0] = f2bf(v.x);
    T[r * 72 + s * 4 + 1] = f2bf(v.y);
    T[r * 72 + s * 4 + 2] = f2bf(v.z);
    T[r * 72 + s * 4 + 3] = f2bf(v.w);
  }
  __syncthreads();
  for (int i = 0; i < 2; i++) {
    int cc = i * 256 + t; int c = cc >> 3; int s2 = cc & 7;
    union { u16 h[8]; uint4 v; } tmp;
    for (int e = 0; e < 8; e++) tmp.h[e] = T[(s2 * 8 + e) * 72 + c];
    *(uint4*)&out[(size_t)(c0 + c) * R + r0 + s2 * 8] = tmp.v;
  }
}

// ---------------- transpose v-part of qkv into Vt[512][8192] ----------------
__global__ __launch_bounds__(256) void k_tv(const u16* __restrict__ qkv, u16* __restrict__ vt) {
  __shared__ u16 T[64 * 72];
  int t = threadIdx.x;
  int r0 = blockIdx.y * 64, d0 = blockIdx.x * 64;
  for (int i = 0; i < 2; i++) {
    int cc = i * 256 + t; int r = cc >> 3; int s = cc & 7;
    *(uint4*)&T[r * 72 + s * 8] = *(const uint4*)&qkv[(size_t)(r0 + r) * 1536 + 1024 + d0 + s * 8];
  }
  __syncthreads();
  for (int i = 0; i < 2; i++) {
    int cc = i * 256 + t; int d = cc >> 3; int s2 = cc & 7;
    union { u16 h[8]; uint4 v; } tmp;
    for (int e = 0; e < 8; e++) tmp.h[e] = T[(s2 * 8 + e) * 72 + d];
    *(uint4*)&vt[(size_t)(d0 + d) * 8192 + r0 + s2 * 8] = tmp.v;
  }
}

// ---------------- GEMM (m97): C = A[M,K] @ Bt[N,K]^T + bias ----------------
__global__ __launch_bounds__(256) void k_gemm(const u16* __restrict__ A, const u16* __restrict__ Bt,
                                              const float* __restrict__ bias,
                                              u16* __restrict__ Cb, float* __restrict__ Cf,
                                              int M, int N, int K) {
  __shared__ u16 As[128 * 64];
  __shared__ u16 Bs[128 * 64];
  const int t = threadIdx.x;
  const int l = t & 63, w = t >> 6;
  const int l16 = l & 15, g = l >> 4;
  const int m0 = blockIdx.y * 128, n0 = blockIdx.x * 128;
  const int wr = (w >> 1) * 64, wc = (w & 1) * 64;
  f32x4 acc[4][4] = {};
  for (int kk = 0; kk < K; kk += 64) {
    __syncthreads();
#pragma unroll
    for (int i = 0; i < 4; i++) {
      int c = i * 256 + t;
      int r = c >> 3, g2 = c & 7;
      int sg = g2 ^ (r & 7);
      __builtin_amdgcn_global_load_lds(
          (const __attribute__((address_space(1))) u32*)(A + (size_t)(m0 + r) * K + kk + sg * 8),
          (__attribute__((address_space(3))) u32*)&As[c * 8], 16, 0, 0);
      __builtin_amdgcn_global_load_lds(
          (const __attribute__((address_space(1))) u32*)(Bt + (size_t)(n0 + r) * K + kk + sg * 8),
          (__attribute__((address_space(3))) u32*)&Bs[c * 8], 16, 0, 0);
    }
    __syncthreads();
#pragma unroll
    for (int kh = 0; kh < 2; kh++) {
      bf16x8 a[4];
#pragma unroll
      for (int mi = 0; mi < 4; mi++) {
        int row = wr + 16 * mi + l16;
        int s = (kh * 4 + g) ^ (row & 7);
        a[mi] = *(const bf16x8*)&As[row * 64 + s * 8];
      }
#pragma unroll
      for (int ni = 0; ni < 4; ni++) {
        int row = wc + 16 * ni + l16;
        int s = (kh * 4 + g) ^ (row & 7);
        bf16x8 b = *(const bf16x8*)&Bs[row * 64 + s * 8];
#pragma unroll
        for (int mi = 0; mi < 4; mi++)
          acc[mi][ni] = __builtin_amdgcn_mfma_f32_16x16x32_bf16(a[mi], b, acc[mi][ni], 0, 0, 0);
      }
    }
  }
#pragma unroll
  for (int ni = 0; ni < 4; ni++) {
    int col = n0 + wc + 16 * ni + l16;
    float bv = bias[col];
#pragma unroll
    for (int mi = 0; mi < 4; mi++) {
      int row0 = m0 + wr + 16 * mi + 4 * g;
#pragma unroll
      for (int r = 0; r < 4; r++) {
        float v = acc[mi][ni][r] + bv;
        if (Cf) Cf[(size_t)(row0 + r) * N + col] = v;
        else    Cb[(size_t)(row0 + r) * N + col] = f2bf(v);
      }
    }
  }
}

// ---------------- k_qkp: P = exp2(C*Q@K^T masked); XCD-chunked flat triangle grid ----------------
__global__ __launch_bounds__(256, 4) void k_qkp(const u16* __restrict__ qkv,
                                                u16* __restrict__ sA, u16* __restrict__ sB, u16* __restrict__ sC,
                                                int nB, float* __restrict__ psum) {
  __shared__ u16 As[128 * 64];
  __shared__ u16 Bs[128 * 64];
  __shared__ float psL[2][128];
  const int h = (int)blockIdx.x;
  const int L = (h & 7) * 260 + (h >> 3);     // XCD-chunked remap (2080 = 8*260)
  const int s0 = 2079 - L;
  int bi = (int)((__builtin_sqrtf(8.0f * s0 + 1.0f) - 1.0f) * 0.5f);
  while ((bi + 1) * (bi + 2) / 2 <= s0) ++bi;
  while (bi * (bi + 1) / 2 > s0) --bi;
  const int bj = s0 - bi * (bi + 1) / 2;
  const int slot = s0;
  const int t = threadIdx.x;
  const int l = t & 63, w = t >> 6;
  const int l16 = l & 15, g = l >> 4;
  const int m0 = bi * 128, n0 = bj * 128;
  const int wr = (w >> 1) * 64, wc = (w & 1) * 64;
  f32x4 acc[4][4] = {};
  for (int kk = 0; kk < 512; kk += 64) {
    __syncthreads();
#pragma unroll
    for (int i = 0; i < 4; i++) {
      int c = i * 256 + t;
      int r = c >> 3, g2 = c & 7;
      int sg = g2 ^ (r & 7);
      __builtin_amdgcn_global_load_lds(
          (const __attribute__((address_space(1))) u32*)(qkv + (size_t)(m0 + r) * 1536 + kk + sg * 8),
          (__attribute__((address_space(3))) u32*)&As[c * 8], 16, 0, 0);
      __builtin_amdgcn_global_load_lds(
          (const __attribute__((address_space(1))) u32*)(qkv + (size_t)(n0 + r) * 1536 + 512 + kk + sg * 8),
          (__attribute__((address_space(3))) u32*)&Bs[c * 8], 16, 0, 0);
    }
    __syncthreads();
#pragma unroll
    for (int kh = 0; kh < 2; kh++) {
      bf16x8 a[4];
#pragma unroll
      for (int mi = 0; mi < 4; mi++) {
        int row = wr + 16 * mi + l16;
        int s = (kh * 4 + g) ^ (row & 7);
        a[mi] = *(const bf16x8*)&As[row * 64 + s * 8];
      }
#pragma unroll
      for (int ni = 0; ni < 4; ni++) {
        int row = wc + 16 * ni + l16;
        int s = (kh * 4 + g) ^ (row & 7);
        bf16x8 b = *(const bf16x8*)&Bs[row * 64 + s * 8];
#pragma unroll
        for (int mi = 0; mi < 4; mi++)
          acc[mi][ni] = __builtin_amdgcn_mfma_f32_16x16x32_bf16(a[mi], b, acc[mi][ni], 0, 0, 0);
      }
    }
  }
  const float C2 = 0.063758718f;              // (1/sqrt(512)) * log2(e)
#pragma unroll
  for (int mi = 0; mi < 4; mi++)
#pragma unroll
    for (int r = 0; r < 4; r++) {
      float s = 0.f;
#pragma unroll
      for (int ni = 0; ni < 4; ni++) {
        float v = acc[mi][ni][r] * C2;
        if (bi == bj && (wc + 16 * ni + l16) > (wr + 16 * mi + 4 * g + r)) v = -1.0e10f;
        float p = __builtin_exp2f(v);
        acc[mi][ni][r] = p;
        s += p;
      }
#pragma unroll
      for (int off = 1; off < 16; off <<= 1) s += __shfl_xor(s, off);
      if (l16 == 0) psL[w & 1][wr + 16 * mi + 4 * g + r] = s;
    }
  __syncthreads();
  if (t < 128) psum[slot * 128 + t] = psL[0][t] + psL[1][t];
  u16* sp = slot < 608 ? sA + (size_t)slot * 16384
          : (slot - 608) < nB ? sB + (size_t)(slot - 608) * 16384
          : sC + (size_t)(slot - 608 - nB) * 16384;
#pragma unroll
  for (int ni = 0; ni < 4; ni++)
#pragma unroll
    for (int mi = 0; mi < 4; mi++)
#pragma unroll
      for (int r = 0; r < 4; r++)
        sp[(wr + 16 * mi + 4 * g + r) * 128 + wc + 16 * ni + l16] = f2bf(acc[mi][ni][r]);
}

// ---------------- k_inv: invl[row] = 1 / sum_bj psum ----------------
__global__ __launch_bounds__(128) void k_inv(const float* __restrict__ psum, float* __restrict__ invl) {
  const int bi = blockIdx.x, t = threadIdx.x;
  const int base = (bi * (bi + 1)) / 2;
  float s = 0.f;
  for (int bj = 0; bj <= bi; bj++) s += psum[(base + bj) * 128 + t];
  invl[bi * 128 + t] = 1.0f / s;
}

// ---------------- k_pv4: 4-segment balanced split over long||short walk (plain launch bounds) ----
__global__ __launch_bounds__(256) void k_pv4(const u16* __restrict__ sA, const u16* __restrict__ sB,
                                             const u16* __restrict__ sC, int nB,
                                             const u16* __restrict__ vt, u16* __restrict__ part) {
  __shared__ u16 As[128 * 64];
  __shared__ u16 Bs[128 * 64];
  const int gx = blockIdx.x;
  const int p = gx >> 4, nj = (gx >> 2) & 3, seg = gx & 3;
  const int L = 2 * (64 - p);
  const int SEG[5] = {0, 33, 65, 98, 130};
  const int S0 = SEG[seg], E0 = SEG[seg + 1];
  const int n0 = nj * 128;
  const int t = threadIdx.x;
  const int l = t & 63, w = t >> 6;
  const int l16 = l & 15, g = l >> 4;
  const int wr = (w >> 1) * 64, wc = (w & 1) * 64;
  const int pb = (p * 4 + nj) * 5;
  f32x4 acc[4][4];

  auto zero = [&]() {
#pragma unroll
    for (int mi = 0; mi < 4; mi++)
#pragma unroll
      for (int ni = 0; ni < 4; ni++) acc[mi][ni] = (f32x4){0.f, 0.f, 0.f, 0.f};
  };
  auto runseg = [&](int bi, int ks0, int ks1) {
    const int slotBase = (bi * (bi + 1)) / 2;
    for (int ks = ks0; ks < ks1; ++ks) {
      const int s_ = slotBase + (ks >> 1);
      const u16* sp = s_ < 608 ? sA + (size_t)s_ * 16384
                    : (s_ - 608) < nB ? sB + (size_t)(s_ - 608) * 16384
                    : sC + (size_t)(s_ - 608 - nB) * 16384;
      const int ko = (ks & 1) * 64;
      const int kk = ks * 64;
      __syncthreads();
#pragma unroll
      for (int i = 0; i < 4; i++) {
        int c = i * 256 + t;
        int r = c >> 3, g2 = c & 7;
        int sg = g2 ^ (r & 7);
        __builtin_amdgcn_global_load_lds(
            (const __attribute__((address_space(1))) u32*)(sp + r * 128 + ko + sg * 8),
            (__attribute__((address_space(3))) u32*)&As[c * 8], 16, 0, 0);
        __builtin_amdgcn_global_load_lds(
            (const __attribute__((address_space(1))) u32*)(vt + (size_t)(n0 + r) * 8192 + kk + sg * 8),
            (__attribute__((address_space(3))) u32*)&Bs[c * 8], 16, 0, 0);
      }
      __syncthreads();
#pragma unroll
      for (int kh = 0; kh < 2; kh++) {
        bf16x8 a[4];
#pragma unroll
        for (int mi = 0; mi < 4; mi++) {
          int row = wr + 16 * mi + l16;
          int s2 = (kh * 4 + g) ^ (row & 7);
          a[mi] = *(const bf16x8*)&As[row * 64 + s2 * 8];
        }
#pragma unroll
        for (int ni = 0; ni < 4; ni++) {
          int row = wc + 16 * ni + l16;
          int s2 = (kh * 4 + g) ^ (row & 7);
          bf16x8 b = *(const bf16x8*)&Bs[row * 64 + s2 * 8];
#pragma unroll
          for (int mi = 0; mi < 4; mi++)
            acc[mi][ni] = __builtin_amdgcn_mfma_f32_16x16x32_bf16(a[mi], b, acc[mi][ni], 0, 0, 0);
        }
      }
    }
  };
  auto write_partial = [&](int q) {
    u16* dst = part + (size_t)(pb + q) * 16384;
#pragma unroll
    for (int mi = 0; mi < 4; mi++)
#pragma unroll
      for (int ni = 0; ni < 4; ni++)
#pragma unroll
        for (int r = 0; r < 4; r++)
          dst[(wr + 16 * mi + 4 * g + r) * 128 + wc + 16 * ni + l16] = f2bf(acc[mi][ni][r]);
  };

  const int biL = 63 - p, biS = p;
  const int lE = min(E0, L);
  const int sS = max(S0, L);
  if (S0 < L) {
    zero();
    runseg(biL, S0, lE);
    write_partial(seg);
    if (sS < E0) {
      zero();
      runseg(biS, sS - L, E0 - L);
      write_partial(4);
    }
  } else {
    zero();
    runseg(biS, S0 - L, E0 - L);
    write_partial(seg);
  }
}

// ---------------- k_compv: sum partials, normalize, write Ob ----------------
__global__ __launch_bounds__(256) void k_compv(const u16* __restrict__ part,
                                               const float* __restrict__ invl, u16* __restrict__ Ob) {
  const int b = blockIdx.x;
  const int which = b >> 7, idx = b & 127;
  const int p = idx >> 2, nj = idx & 3;
  const int bi = which ? p : 63 - p;
  const int m0 = bi * 128, n0 = nj * 128;
  const int L = 2 * (64 - p);
  const int SEG[5] = {0, 33, 65, 98, 130};
  const int pb = (p * 4 + nj) * 5;
  int inc[5];
  int spans = 0;
  for (int s = 0; s < 4; s++) {
    if (which == 0) inc[s] = (SEG[s] < L);
    else            inc[s] = (SEG[s] >= L);
    if (SEG[s] < L && SEG[s + 1] > L) spans = 1;
  }
  inc[4] = which ? spans : 0;
  const int t = threadIdx.x;
#pragma unroll
  for (int e = 0; e < 8; e++) {
    int pos = (e * 256 + t) * 8;
    int row = pos >> 7, col = pos & 127;
    float o[8] = {};
    for (int q = 0; q < 5; q++) {
      if (!inc[q]) continue;
      const uint4* src = (const uint4*)(part + (size_t)(pb + q) * 16384);
      uint4 v = src[pos >> 3];
      union { uint4 u; u16 h[8]; } un; un.u = v;
#pragma unroll
      for (int j = 0; j < 8; j++) o[j] += bf2f(un.h[j]);
    }
    float inv = invl[m0 + row];
    union { u16 h[8]; uint4 u; } pk;
#pragma unroll
    for (int j = 0; j < 8; j++) pk.h[j] = f2bf(o[j] * inv);
    *(uint4*)&Ob[(size_t)(m0 + row) * 512 + n0 + col] = pk.u;
  }
}

extern "C" void kernel_launch(void* const* d_in, const int* in_sizes, int n_in,
                              void* d_out, int out_size, void* d_ws, size_t ws_size,
                              hipStream_t stream) {
  const float* x     = (const float*)d_in[0];
  const float* w_qkv = (const float*)d_in[1];
  const float* b_qkv = (const float*)d_in[2];
  const float* w_out = (const float*)d_in[3];
  const float* b_out = (const float*)d_in[4];
  float* out = (float*)d_out;
  char* ws = (char*)d_ws;
  // base layout
  u16* xb    = (u16*)(ws);               // [8192][1024] bf16 (dead after gemm1 -> P region A)
  u16* wqkvT = (u16*)(ws + 16777216);    // [1536][1024] bf16 (dead after gemm1 -> P region A)
  u16* woutT = (u16*)(ws + 19922944);    // [1024][512]  bf16 (live to the end)
  u16* qkv   = (u16*)(ws + 20971520);    // [8192][1536] bf16 (dead after k_qkp -> pv4 partials)
  u16* vt    = (u16*)(ws + 46137344);    // [512][8192]  bf16
  u16* Ob    = (u16*)(ws + 54525952);    // [8192][512]  bf16

  // P slots: 2080 x 32KB. A: 608 slots; B: tail of ws; C: d_out. psum/invl in d_out after C.
  u16* sA = (u16*)ws;
  u16* sB = (u16*)(ws + 62914560);
  long nBl = ((long)ws_size - 62914560) / 32768;
  int nB = nBl > 1472 ? 1472 : (int)(nBl < 0 ? 0 : nBl);
  int nC = 2080 - 608 - nB; if (nC < 0) nC = 0;
  u16* sC = (u16*)d_out;
  float* psum = (float*)((u16*)d_out + (size_t)nC * 16384);
  float* invl = psum + 2080 * 128;
  // pv4 partials: 640 x 32KB bf16 = 20.97 MB in dead qkv region (25.17 MB)
  u16* part = (u16*)(ws + 20971520);

  k_cvt<<<4096, 256, 0, stream>>>(x, xb, 8192 * 1024);
  k_tcvt<<<dim3(24, 16), 256, 0, stream>>>(w_qkv, wqkvT, 1024, 1536);
  k_tcvt<<<dim3(16, 8), 256, 0, stream>>>(w_out, woutT, 512, 1024);
  k_gemm<<<dim3(12, 64), 256, 0, stream>>>(xb, wqkvT, b_qkv, qkv, nullptr, 8192, 1536, 1024);
  k_tv<<<dim3(8, 128), 256, 0, stream>>>(qkv, vt);
  k_qkp<<<2080, 256, 0, stream>>>(qkv, sA, sB, sC, nB, psum);
  k_inv<<<64, 128, 0, stream>>>(psum, invl);
  k_pv4<<<512, 256, 0, stream>>>(sA, sB, sC, nB, vt, part);
  k_compv<<<256, 256, 0, stream>>>(part, invl, Ob);
  k_gemm<<<dim3(8, 64), 256, 0, stream>>>(Ob, woutT, b_out, nullptr, out, 8192, 1024, 512);
}